// Round 1
// baseline (216.290 us; speedup 1.0000x reference)
//
#include <hip/hip_runtime.h>

#define N_ 32
#define C_ 256
#define G_ 16
#define HW_ 3136          // 56*56
#define HW4_ 784          // HW/4
#define NBIN_ 8           // bins per batch-image; LPT-balanced (32 rows each here)
#define BLK_ 1024
#define NWAVE_ (BLK_ / 64)
#define EPS_ 1e-12f

typedef float vf4 __attribute__((ext_vector_type(4)));

// Integer inputs may arrive as int32 or int64; group_sizes[1]==24 in int32
// layout, ==0 (high word of gs[0]) in int64 LE layout. Values < 2^31 so the
// low word is the value in int64 mode.
__device__ __forceinline__ int rd_int(const int* __restrict__ p, int i, bool is64) {
    return is64 ? p[2 * i] : p[i];
}

// ---------------------------------------------------------------------------
// Fused kernel: one block per (n, bin). Bins are an LPT packing of the 16
// groups into 8 bins (deterministic, recomputed identically in every block
// from group_sizes; for gs = [8,24,8,16,32,...] every bin is exactly 32 rows).
// A block owns WHOLE groups, so reduce -> stats -> normalize needs no
// cross-block communication: no workspace, no second launch, no grid sync.
// Phase 2 re-reads the block's ~392 KB working set immediately after phase 1
// wrote it into L2/L3 (all of x = 103 MB < 256 MB Infinity Cache), so the
// second read should not touch HBM.
// ---------------------------------------------------------------------------
__global__ __launch_bounds__(BLK_) void vgn_fused(
    const float* __restrict__ x,
    const int*   __restrict__ indexes,
    const int*   __restrict__ group_sizes,
    const float* __restrict__ weight,
    const float* __restrict__ bias,
    float*       __restrict__ out)
{
    const bool is64 = (group_sizes[1] == 0);
    const int n   = blockIdx.x >> 3;           // NBIN_ == 8
    const int bin = blockIdx.x & (NBIN_ - 1);
    const int tid = threadIdx.x;

    __shared__ int   sGs[G_], sPg[G_];         // group sizes + channel prefix
    __shared__ int   sOrd[G_], sLoad[NBIN_];   // LPT scratch (thread 0)
    __shared__ int   sGrpId[G_];               // global group ids in this bin
    __shared__ int   sGrpStart[G_ + 1];        // row offsets within bin
    __shared__ int   sGrpCnt, sNRows;
    __shared__ int   sRowSrc[C_];              // per-bin-row source row in x
    __shared__ float sRowScale[C_], sRowShift[C_];
    __shared__ float sMu[G_], sIvar[G_];
    __shared__ float sRed[2 * NWAVE_];

    // ---- setup: LPT bin packing (scalar, ~16x16 ops, identical in all blocks)
    if (tid == 0) {
        int P = 0;
        for (int k = 0; k < G_; k++) {
            int g = rd_int(group_sizes, k, is64);
            sGs[k] = g; sPg[k] = P; P += g;
            sOrd[k] = k;
        }
        // selection sort by size descending (ties: lower id first -> stable)
        for (int a = 0; a < G_; a++) {
            int best = a;
            for (int b = a + 1; b < G_; b++)
                if (sGs[sOrd[b]] > sGs[sOrd[best]]) best = b;
            int t = sOrd[a]; sOrd[a] = sOrd[best]; sOrd[best] = t;
        }
        for (int b = 0; b < NBIN_; b++) sLoad[b] = 0;
        int cnt = 0, rows = 0;
        for (int a = 0; a < G_; a++) {
            int bmin = 0;
            for (int b = 1; b < NBIN_; b++) if (sLoad[b] < sLoad[bmin]) bmin = b;
            int gid = sOrd[a];
            if (bmin == bin) {
                sGrpId[cnt]    = gid;
                sGrpStart[cnt] = rows;
                rows += sGs[gid];
                cnt++;
            }
            sLoad[bmin] += sGs[gid];
        }
        sGrpStart[cnt] = rows;
        sGrpCnt = cnt;
        sNRows  = rows;
    }
    __syncthreads();

    const int nGrp  = sGrpCnt;
    const int nRows = sNRows;

    // ---- parallel: per-row source index (gather pattern; write-back target
    // is the SAME flat row, since reverse_indexes is the inverse permutation)
    if (tid < nRows) {
        int a = 0;
        while (!(tid >= sGrpStart[a] && tid < sGrpStart[a + 1])) a++;
        int j = sPg[sGrpId[a]] + (tid - sGrpStart[a]);
        sRowSrc[tid] = rd_int(indexes, n * C_ + j, is64);
    }
    __syncthreads();

    const int wave = tid >> 6;
    const int lane = tid & 63;

    // ---- phase 1: per-group sum / sumsq over gsz*3136 elements
    for (int a = 0; a < nGrp; a++) {
        const int r0  = sGrpStart[a];
        const int gsz = sGrpStart[a + 1] - r0;
        const int tot = gsz * HW4_;
        float s = 0.f, s2 = 0.f;
        for (int idx = tid; idx < tot; idx += BLK_) {
            int r   = idx / HW4_;              // const divisor -> magic mul
            int col = idx - r * HW4_;
            const vf4* p = (const vf4*)(x + (size_t)sRowSrc[r0 + r] * HW_);
            vf4 v = p[col];
            s += v.x + v.y + v.z + v.w;
            s2 = fmaf(v.x, v.x, s2);
            s2 = fmaf(v.y, v.y, s2);
            s2 = fmaf(v.z, v.z, s2);
            s2 = fmaf(v.w, v.w, s2);
        }
        #pragma unroll
        for (int off = 32; off > 0; off >>= 1) {
            s  += __shfl_down(s,  off);
            s2 += __shfl_down(s2, off);
        }
        if (lane == 0) { sRed[wave] = s; sRed[NWAVE_ + wave] = s2; }
        __syncthreads();
        if (tid == 0) {
            float S = 0.f, S2 = 0.f;
            for (int w = 0; w < NWAVE_; w++) { S += sRed[w]; S2 += sRed[NWAVE_ + w]; }
            float cnt = (float)gsz * (float)HW_;
            float mu  = S / cnt;
            float var = (S2 - mu * S) / (cnt - 1.0f);   // ddof=1, matches ref
            sMu[a]   = mu;
            sIvar[a] = rsqrtf(var + EPS_);
        }
        __syncthreads();   // stats visible + sRed reusable next group
    }

    // ---- per-row scale/shift
    if (tid < nRows) {
        int a = 0;
        while (!(tid >= sGrpStart[a] && tid < sGrpStart[a + 1])) a++;
        int j = sPg[sGrpId[a]] + (tid - sGrpStart[a]);
        float sc = sIvar[a] * weight[j];
        sRowScale[tid] = sc;
        sRowShift[tid] = fmaf(-sMu[a], sc, bias[j]);
    }
    __syncthreads();

    // ---- phase 2: normalize + affine; x re-read is L2/L3-warm; out is never
    // re-read -> nontemporal stores
    const int tot = nRows * HW4_;
    for (int idx = tid; idx < tot; idx += BLK_) {
        int r   = idx / HW4_;
        int col = idx - r * HW4_;
        const size_t base = (size_t)sRowSrc[r] * HW4_;   // in vf4 units
        vf4 v = ((const vf4*)x)[base + col];
        float sc = sRowScale[r], sh = sRowShift[r];
        vf4 o;
        o.x = fmaf(v.x, sc, sh);
        o.y = fmaf(v.y, sc, sh);
        o.z = fmaf(v.z, sc, sh);
        o.w = fmaf(v.w, sc, sh);
        __builtin_nontemporal_store(o, (vf4*)out + base + col);
    }
}

// ---------------------------------------------------------------------------
extern "C" void kernel_launch(void* const* d_in, const int* in_sizes, int n_in,
                              void* d_out, int out_size, void* d_ws, size_t ws_size,
                              hipStream_t stream) {
    const float* x           = (const float*)d_in[0];
    const float* weight      = (const float*)d_in[1];
    const float* bias        = (const float*)d_in[2];
    const int*   group_sizes = (const int*)  d_in[3];
    const int*   indexes     = (const int*)  d_in[4];
    // d_in[5] = reverse_indexes (unused: scatter target == gather source)

    dim3 grid(N_ * NBIN_), block(BLK_);
    vgn_fused<<<grid, block, 0, stream>>>(x, indexes, group_sizes,
                                          weight, bias, (float*)d_out);
}

// Round 2
// 214.594 us; speedup vs baseline: 1.0079x; 1.0079x over previous
//
#include <hip/hip_runtime.h>

#define N_ 32
#define C_ 256
#define G_ 16
#define HW_ 3136          // 56*56
#define HW4_ 784          // HW/4 (vf4 units); 784 = 24*32 + 16
#define NBIN_ 8           // bins per batch-image; LPT-balanced (32 rows each here)
#define BLK_ 1024
#define EPS_ 1e-12f

typedef float vf4 __attribute__((ext_vector_type(4)));

// Integer inputs may arrive as int32 or int64; group_sizes[1]==24 in int32
// layout, ==0 (high word of gs[0]) in int64 LE layout. Values < 2^31 so the
// low word is the value in int64 mode.
__device__ __forceinline__ int rd_int(const int* __restrict__ p, int i, bool is64) {
    return is64 ? p[2 * i] : p[i];
}

// ---------------------------------------------------------------------------
// Fused kernel, v2: one block per (n, bin); bins are an LPT packing of the 16
// groups into 8 bins (32 rows each for this gs). Block owns whole groups ->
// no cross-block comms, no workspace, single launch.
//
// v2 structural change vs v1 (which hit only 2.37 TB/s): static 32-threads-
// per-row mapping. Row base address is ONE hoisted LDS read; the inner loops
// have COMPILE-TIME trip counts (24 full + 16-lane tail) and affine addresses,
// so the compiler can unroll and keep many vf4 loads in flight (v1's rolled
// loops with LDS+div in the address chain left ~0.2 loads/wave outstanding).
// Phase 1 also drops from 2 barriers per group to 1 barrier total.
// ---------------------------------------------------------------------------
__global__ __launch_bounds__(BLK_) void vgn_fused(
    const float* __restrict__ x,
    const int*   __restrict__ indexes,
    const int*   __restrict__ group_sizes,
    const float* __restrict__ weight,
    const float* __restrict__ bias,
    float*       __restrict__ out)
{
    const bool is64 = (group_sizes[1] == 0);
    const int n   = blockIdx.x >> 3;           // NBIN_ == 8
    const int bin = blockIdx.x & (NBIN_ - 1);
    const int tid = threadIdx.x;

    __shared__ int   sGs[G_], sPg[G_];         // group sizes + channel prefix
    __shared__ int   sOrd[G_], sLoad[NBIN_];   // LPT scratch (thread 0)
    __shared__ int   sGrpId[G_];               // global group ids in this bin
    __shared__ int   sGrpStart[G_ + 1];        // row offsets within bin
    __shared__ int   sGrpCnt, sNRows;
    __shared__ int   sRowSrc[C_];              // per-bin-row source row in x
    __shared__ float sRowS[C_], sRowS2[C_];    // per-row sum / sumsq
    __shared__ float sRowScale[C_], sRowShift[C_];
    __shared__ float sMu[G_], sIvar[G_];

    // ---- setup: LPT bin packing (scalar, identical in all blocks)
    if (tid == 0) {
        int P = 0;
        for (int k = 0; k < G_; k++) {
            int g = rd_int(group_sizes, k, is64);
            sGs[k] = g; sPg[k] = P; P += g;
            sOrd[k] = k;
        }
        for (int a = 0; a < G_; a++) {          // selection sort, size desc
            int best = a;
            for (int b = a + 1; b < G_; b++)
                if (sGs[sOrd[b]] > sGs[sOrd[best]]) best = b;
            int t = sOrd[a]; sOrd[a] = sOrd[best]; sOrd[best] = t;
        }
        for (int b = 0; b < NBIN_; b++) sLoad[b] = 0;
        int cnt = 0, rows = 0;
        for (int a = 0; a < G_; a++) {
            int bmin = 0;
            for (int b = 1; b < NBIN_; b++) if (sLoad[b] < sLoad[bmin]) bmin = b;
            int gid = sOrd[a];
            if (bmin == bin) {
                sGrpId[cnt]    = gid;
                sGrpStart[cnt] = rows;
                rows += sGs[gid];
                cnt++;
            }
            sLoad[bmin] += sGs[gid];
        }
        sGrpStart[cnt] = rows;
        sGrpCnt = cnt;
        sNRows  = rows;
    }
    __syncthreads();

    const int nGrp  = sGrpCnt;
    const int nRows = sNRows;

    // ---- per-row source index (gather; write-back target is the SAME flat
    // row, since reverse_indexes is the inverse permutation)
    if (tid < nRows) {
        int a = 0;
        while (tid >= sGrpStart[a + 1]) a++;
        int j = sPg[sGrpId[a]] + (tid - sGrpStart[a]);
        sRowSrc[tid] = rd_int(indexes, n * C_ + j, is64);
    }
    __syncthreads();

    const int rowT   = tid >> 5;               // 32 threads per row
    const int lane32 = tid & 31;

    // ---- phase 1: per-row sum / sumsq (compile-time inner loop, base hoisted)
    for (int r = rowT; r < nRows; r += 32) {
        const vf4* p4 = (const vf4*)(x + (size_t)sRowSrc[r] * HW_);
        float s = 0.f, s2 = 0.f;
        #pragma unroll 8
        for (int it = 0; it < 24; ++it) {
            vf4 v = p4[lane32 + (it << 5)];
            s  += v.x + v.y + v.z + v.w;
            s2  = fmaf(v.x, v.x, s2);
            s2  = fmaf(v.y, v.y, s2);
            s2  = fmaf(v.z, v.z, s2);
            s2  = fmaf(v.w, v.w, s2);
        }
        if (lane32 < 16) {                      // 784 = 24*32 + 16 tail
            vf4 v = p4[768 + lane32];
            s  += v.x + v.y + v.z + v.w;
            s2  = fmaf(v.x, v.x, s2);
            s2  = fmaf(v.y, v.y, s2);
            s2  = fmaf(v.z, v.z, s2);
            s2  = fmaf(v.w, v.w, s2);
        }
        #pragma unroll                           // 32-lane sub-reduce (per half-wave)
        for (int off = 16; off > 0; off >>= 1) {
            s  += __shfl_down(s,  off);
            s2 += __shfl_down(s2, off);
        }
        if (lane32 == 0) { sRowS[r] = s; sRowS2[r] = s2; }
    }
    __syncthreads();

    // ---- group stats: one lane per group (groups-in-bin <= G_)
    if (tid < nGrp) {
        float S = 0.f, S2 = 0.f;
        const int r0 = sGrpStart[tid], r1 = sGrpStart[tid + 1];
        for (int r = r0; r < r1; r++) { S += sRowS[r]; S2 += sRowS2[r]; }
        const float cnt = (float)(r1 - r0) * (float)HW_;
        const float mu  = S / cnt;
        const float var = (S2 - mu * S) / (cnt - 1.0f);   // ddof=1, matches ref
        sMu[tid]   = mu;
        sIvar[tid] = rsqrtf(var + EPS_);
    }
    __syncthreads();

    // ---- per-row scale/shift
    if (tid < nRows) {
        int a = 0;
        while (tid >= sGrpStart[a + 1]) a++;
        int j = sPg[sGrpId[a]] + (tid - sGrpStart[a]);
        float sc = sIvar[a] * weight[j];
        sRowScale[tid] = sc;
        sRowShift[tid] = fmaf(-sMu[a], sc, bias[j]);
    }
    __syncthreads();

    // ---- phase 2: normalize + affine; x re-read is L3-warm (103 MB < 256 MB
    // Infinity Cache); out never re-read -> nontemporal stores that also keep
    // the cache clean for other blocks' phase-2 reads.
    for (int r = rowT; r < nRows; r += 32) {
        const size_t base = (size_t)sRowSrc[r] * HW4_;   // vf4 units
        const vf4* p4 = (const vf4*)x + base;
        vf4*       o4 = (vf4*)out     + base;
        const float sc = sRowScale[r], sh = sRowShift[r];
        #pragma unroll 8
        for (int it = 0; it < 24; ++it) {
            const int i = lane32 + (it << 5);
            vf4 v = p4[i];
            vf4 o;
            o.x = fmaf(v.x, sc, sh);
            o.y = fmaf(v.y, sc, sh);
            o.z = fmaf(v.z, sc, sh);
            o.w = fmaf(v.w, sc, sh);
            __builtin_nontemporal_store(o, o4 + i);
        }
        if (lane32 < 16) {
            const int i = 768 + lane32;
            vf4 v = p4[i];
            vf4 o;
            o.x = fmaf(v.x, sc, sh);
            o.y = fmaf(v.y, sc, sh);
            o.z = fmaf(v.z, sc, sh);
            o.w = fmaf(v.w, sc, sh);
            __builtin_nontemporal_store(o, o4 + i);
        }
    }
}

// ---------------------------------------------------------------------------
extern "C" void kernel_launch(void* const* d_in, const int* in_sizes, int n_in,
                              void* d_out, int out_size, void* d_ws, size_t ws_size,
                              hipStream_t stream) {
    const float* x           = (const float*)d_in[0];
    const float* weight      = (const float*)d_in[1];
    const float* bias        = (const float*)d_in[2];
    const int*   group_sizes = (const int*)  d_in[3];
    const int*   indexes     = (const int*)  d_in[4];
    // d_in[5] = reverse_indexes (unused: scatter target == gather source)

    dim3 grid(N_ * NBIN_), block(BLK_);
    vgn_fused<<<grid, block, 0, stream>>>(x, indexes, group_sizes,
                                          weight, bias, (float*)d_out);
}

// Round 3
// 202.252 us; speedup vs baseline: 1.0694x; 1.0610x over previous
//
#include <hip/hip_runtime.h>

#define N_ 32
#define C_ 256
#define G_ 16
#define HW_ 3136          // 56*56
#define HW4_ 784          // HW/4 in vf4 units; 784 = 3*256 + 16
#define EPS_ 1e-12f

typedef float vf4 __attribute__((ext_vector_type(4)));
typedef float vf2 __attribute__((ext_vector_type(2)));

// Integer inputs may arrive as int32 or int64; group_sizes[1]==24 in int32
// layout, ==0 (high word of gs[0]) in int64 LE layout. Values < 2^31 so the
// low word is the value in int64 mode.
__device__ __forceinline__ int rd_int(const int* __restrict__ p, int i, bool is64) {
    return is64 ? p[2 * i] : p[i];
}

__device__ __forceinline__ void acc4(const vf4 v, float& s, float& s2) {
    s += v.x + v.y + v.z + v.w;
    s2 = fmaf(v.x, v.x, s2);
    s2 = fmaf(v.y, v.y, s2);
    s2 = fmaf(v.z, v.z, s2);
    s2 = fmaf(v.w, v.w, s2);
}

__device__ __forceinline__ vf4 aff(const vf4 v, float sc, float sh) {
    vf4 r;
    r.x = fmaf(v.x, sc, sh);
    r.y = fmaf(v.y, sc, sh);
    r.z = fmaf(v.z, sc, sh);
    r.w = fmaf(v.w, sc, sh);
    return r;
}

// ---------------------------------------------------------------------------
// v4: back to 2 kernels. Lesson from v2/v3 (fused, 256 blocks x 1024): fusion
// halved TLP (16 waves/CU) and plateaued at 2.38 TB/s; the old 2-kernel
// baseline's kernel-time was ~72 us BECAUSE it ran 32 waves/CU. L3 keeps all
// of x (103 MB < 256 MB) warm ACROSS the kernel boundary, so kernel 2's
// re-read costs no HBM traffic regardless of fusion.
//
// Both kernels: 4096 blocks x 256 threads (8 blocks/CU co-resident = 32
// waves/CU, launch_bounds caps VGPR <= 64), 2 rows per block, and ALL vf4
// loads issued into named registers up front -> 6-8 outstanding loads/wave.
// ---------------------------------------------------------------------------

// Kernel 1: per permuted row pair: S / S2, plain stores to rsums[row*2+{0,1}].
__global__ __launch_bounds__(256, 8) void vgn_reduce(
    const float* __restrict__ x,
    const int*   __restrict__ indexes,
    const int*   __restrict__ group_sizes,
    float*       __restrict__ rsums)
{
    const bool is64 = (group_sizes[1] == 0);
    const int t  = threadIdx.x;
    const int r0 = blockIdx.x * 2;

    const int src0 = rd_int(indexes, r0,     is64);
    const int src1 = rd_int(indexes, r0 + 1, is64);
    const vf4* p0 = (const vf4*)x + (size_t)src0 * HW4_;
    const vf4* p1 = (const vf4*)x + (size_t)src1 * HW4_;

    // 6 unconditional + 2 tail loads, all issued before any consumption
    vf4 a0 = p0[t], b0 = p0[t + 256], c0 = p0[t + 512];
    vf4 a1 = p1[t], b1 = p1[t + 256], c1 = p1[t + 512];

    float sA = 0.f, qA = 0.f, sB = 0.f, qB = 0.f;
    if (t < 16) {                       // 784 = 3*256 + 16 tail
        vf4 d0 = p0[768 + t];
        vf4 d1 = p1[768 + t];
        acc4(d0, sA, qA);
        acc4(d1, sB, qB);
    }
    acc4(a0, sA, qA); acc4(b0, sA, qA); acc4(c0, sA, qA);
    acc4(a1, sB, qB); acc4(b1, sB, qB); acc4(c1, sB, qB);

    #pragma unroll
    for (int off = 32; off > 0; off >>= 1) {
        sA += __shfl_down(sA, off);
        qA += __shfl_down(qA, off);
        sB += __shfl_down(sB, off);
        qB += __shfl_down(qB, off);
    }

    __shared__ float red[4][4];         // [wave][val]
    if ((t & 63) == 0) {
        const int w = t >> 6;
        red[w][0] = sA; red[w][1] = qA; red[w][2] = sB; red[w][3] = qB;
    }
    __syncthreads();
    if (t < 4)                          // {S,S2} row0, {S,S2} row1
        rsums[r0 * 2 + t] = red[0][t] + red[1][t] + red[2][t] + red[3][t];
}

// Kernel 2: per permuted row pair: combine the group's contiguous per-row
// partials (gsz <= 32) into stats, then normalize + affine. Write-back target
// is the SAME flat row (reverse permutation is the inverse of the gather).
// x loads issued FIRST so the stats prologue hides under them; nontemporal
// stores keep L3 clean for other blocks' x reads.
__global__ __launch_bounds__(256, 8) void vgn_norm(
    const float* __restrict__ x,
    const int*   __restrict__ indexes,
    const int*   __restrict__ group_sizes,
    const float* __restrict__ weight,
    const float* __restrict__ bias,
    const float* __restrict__ rsums,
    float*       __restrict__ out)
{
    const bool is64 = (group_sizes[1] == 0);
    const int t  = threadIdx.x;
    const int r0 = blockIdx.x * 2;
    const int n  = r0 >> 8;

    const int src0 = rd_int(indexes, r0,     is64);
    const int src1 = rd_int(indexes, r0 + 1, is64);
    const vf4* p0 = (const vf4*)x + (size_t)src0 * HW4_;
    const vf4* p1 = (const vf4*)x + (size_t)src1 * HW4_;
    vf4* o0 = (vf4*)out + (size_t)src0 * HW4_;
    vf4* o1 = (vf4*)out + (size_t)src1 * HW4_;

    // issue the streaming loads before the stats prologue
    vf4 a0 = p0[t], b0 = p0[t + 256], c0 = p0[t + 512];
    vf4 a1 = p1[t], b1 = p1[t + 256], c1 = p1[t + 512];
    vf4 d0, d1;
    const bool tail = (t < 16);
    if (tail) { d0 = p0[768 + t]; d1 = p1[768 + t]; }

    __shared__ float sScale[2], sShift[2];
    if (t < 64) {                       // half-wave per row
        const int half = t >> 5;
        const int l    = t & 31;
        const int j    = (r0 + half) & 255;
        int g = 0, P = 0, Pg = 0;
        #pragma unroll
        for (int k = 0; k < G_; k++) {
            P += rd_int(group_sizes, k, is64);
            if (j >= P) { g++; Pg = P; }
        }
        const int gsz = rd_int(group_sizes, g, is64);
        float a = 0.f, b = 0.f;
        if (l < gsz) {
            const vf2 pr = ((const vf2*)rsums)[n * C_ + Pg + l];
            a = pr.x; b = pr.y;
        }
        #pragma unroll
        for (int off = 16; off > 0; off >>= 1) {
            a += __shfl_down(a, off, 32);
            b += __shfl_down(b, off, 32);
        }
        if (l == 0) {
            const float cnt = (float)gsz * (float)HW_;
            const float mu  = a / cnt;
            const float var = (b - mu * a) / (cnt - 1.0f);   // ddof=1
            const float ivr = rsqrtf(var + EPS_);
            const float sc  = ivr * weight[j];
            sScale[half] = sc;
            sShift[half] = fmaf(-mu, sc, bias[j]);
        }
    }
    __syncthreads();

    const float sc0 = sScale[0], sh0 = sShift[0];
    const float sc1 = sScale[1], sh1 = sShift[1];

    __builtin_nontemporal_store(aff(a0, sc0, sh0), o0 + t);
    __builtin_nontemporal_store(aff(b0, sc0, sh0), o0 + t + 256);
    __builtin_nontemporal_store(aff(c0, sc0, sh0), o0 + t + 512);
    __builtin_nontemporal_store(aff(a1, sc1, sh1), o1 + t);
    __builtin_nontemporal_store(aff(b1, sc1, sh1), o1 + t + 256);
    __builtin_nontemporal_store(aff(c1, sc1, sh1), o1 + t + 512);
    if (tail) {
        __builtin_nontemporal_store(aff(d0, sc0, sh0), o0 + 768 + t);
        __builtin_nontemporal_store(aff(d1, sc1, sh1), o1 + 768 + t);
    }
}

// ---------------------------------------------------------------------------
extern "C" void kernel_launch(void* const* d_in, const int* in_sizes, int n_in,
                              void* d_out, int out_size, void* d_ws, size_t ws_size,
                              hipStream_t stream) {
    const float* x           = (const float*)d_in[0];
    const float* weight      = (const float*)d_in[1];
    const float* bias        = (const float*)d_in[2];
    const int*   group_sizes = (const int*)  d_in[3];
    const int*   indexes     = (const int*)  d_in[4];
    // d_in[5] = reverse_indexes (unused: scatter target == gather source)

    float* rsums = (float*)d_ws;        // N_*C_*2 floats = 64 KB, fully written
                                        // by vgn_reduce (no init, no atomics)

    dim3 grid(N_ * C_ / 2), block(256); // 4096 blocks: 8/CU, 32 waves/CU
    vgn_reduce<<<grid, block, 0, stream>>>(x, indexes, group_sizes, rsums);
    vgn_norm  <<<grid, block, 0, stream>>>(x, indexes, group_sizes,
                                           weight, bias, rsums, (float*)d_out);
}